// Round 10
// baseline (121.437 us; speedup 1.0000x reference)
//
#include <hip/hip_runtime.h>
#include <hip/hip_cooperative_groups.h>

namespace cg = cooperative_groups;

#define NPOS 8500
#define BB 4
#define EMB 32
#define KP 16
#define MOM 528            /* S[16] + M[16][32] coefficients per batch */
#define NBLK 64            /* j-chunks per batch == tiles per batch */
#define JPB 133            /* j's per chunk */
#define JPS 8              /* j's per 32-lane subgroup (18 subgroups, last ~idle) */
#define TOUT 133           /* output positions per tile; 64*133 = 8512 */
#define STG 137            /* staged x idx [0,137): pos start-2 .. start+134 */
#define STR 138            /* LDS row stride (floats), rows 8B-aligned */
#define THR 576            /* 9 waves: 8 conv waves + 1 edge wave */

__device__ __constant__ float c_invf[KP] = {
    1.f, 1.f, 0.5f, 1.f/6.f, 1.f/24.f, 1.f/120.f, 1.f/720.f, 1.f/5040.f,
    1.f/40320.f, 1.f/362880.f, 1.f/3628800.f, 1.f/39916800.f,
    1.f/479001600.f, 1.f/6227020800.f, 1.f/87178291200.f, 1.f/1307674368000.f};

// shallow power tree: p[1..15] = v^k, depth <= 4 mults
__device__ __forceinline__ void powtree(float v, float* p) {
    const float v2 = v * v;
    const float v4 = v2 * v2;
    const float v8 = v4 * v4;
    p[1] = v;          p[2] = v2;         p[3] = v2 * v;
    p[4] = v4;         p[5] = v4 * v;     p[6] = v4 * v2;
    p[7] = v4 * p[3];  p[8] = v8;         p[9] = v8 * v;
    p[10] = v8 * v2;   p[11] = v8 * p[3]; p[12] = v8 * v4;
    p[13] = v8 * p[5]; p[14] = v8 * p[6]; p[15] = v8 * p[7];
}

// ============ fused: partial moments -> grid sync -> reduce/x-gen/conv1/conv2 ============
__global__ __launch_bounds__(THR, 2) void fused_kernel(
    const float* __restrict__ inten, const int* __restrict__ angle,
    const float* __restrict__ emb,
    const float* __restrict__ w1, const float* __restrict__ b1,
    const float* __restrict__ w2, const float* __restrict__ b2,
    float* __restrict__ part, float* __restrict__ out)
{
    __shared__ float moms[MOM];
    __shared__ float pool[2 * EMB * STR];   // 8832 floats; phase A: red[9][528] (4752)
    float (*xs)[STR] = (float(*)[STR])pool;
    float (*hs)[STR] = (float(*)[STR])(pool + EMB * STR);
    float (*red)[MOM] = (float(*)[MOM])pool;

    const int t = threadIdx.x;
    const int b = blockIdx.x >> 6;      // 64 tiles/batch
    const int tile = blockIdx.x & 63;   // == this block's j-chunk
    const int e = t & 31;

    // ================= PHASE A: partial moments for chunk == tile =================
    {
        const int sub = t >> 5;                 // 18 subgroups of 32 lanes
        const int jlo = tile * JPB;
        const int jhi = min(jlo + JPB, NPOS);
        const int js = jlo + sub * JPS;
        const int je = min(js + JPS, jhi);

        float accM[KP], accS[KP];
#pragma unroll
        for (int k = 0; k < KP; ++k) { accM[k] = 0.f; accS[k] = 0.f; }

        const float* ib = inten + b * NPOS;
        const int* ab = angle + b * NPOS;
        for (int j = js; j < je; ++j) {
            const float v = ib[j] * 0.01f;
            const float ev = emb[ab[j] * EMB + e];   // 128B row per 32-lane group
            float p[KP];
            powtree(v, p);
            accM[0] += ev;
            accS[0] += 1.0f;
#pragma unroll
            for (int k = 1; k < KP; ++k) {
                accM[k] = fmaf(p[k], ev, accM[k]);
                accS[k] += p[k];
            }
        }

        // fold the wave's two subgroups (fixed order -> deterministic)
#pragma unroll
        for (int k = 0; k < KP; ++k) {
            accM[k] += __shfl_xor(accM[k], 32);
            accS[k] += __shfl_xor(accS[k], 32);
        }
        const int wv = t >> 6;
        if ((t & 32) == 0) {
#pragma unroll
            for (int k = 0; k < KP; ++k) red[wv][KP + k * EMB + e] = accM[k];
            if (e == 0) {
#pragma unroll
                for (int k = 0; k < KP; ++k) red[wv][k] = accS[k];
            }
        }
        __syncthreads();
        for (int i = t; i < MOM; i += THR) {
            float s = 0.f;
#pragma unroll
            for (int u = 0; u < 9; ++u) s += red[u][i];
            part[((size_t)b * MOM + i) * NBLK + tile] = s;
        }
    }
    __threadfence();
    cg::this_grid().sync();
    __syncthreads();   // ensure red-reads done before pool reuse (paranoia; sync above covers it)

    // ================= PHASE B: reduce -> x(Horner) -> conv1 -> conv2 =================
    const int start = tile * TOUT;

    // preload this thread's x-gen inputs (u<0 == invalid sentinel); inten is L2-hot now
    float uu[8];
#pragma unroll
    for (int q = 0; q < 8; ++q) {
        const int i = t + q * THR;
        float u = -1.0f;
        if (i < STG * EMB) {
            const int pos = i >> 5;
            const int gp = start - 2 + pos;
            if (gp >= 0 && gp < NPOS) u = inten[b * NPOS + gp] * 0.01f;
        }
        uu[q] = u;
    }

    // reduce this batch's partials: one coeff per thread, 16 x float4, 4-way ILP
    if (t < MOM) {
        const float4* pr = (const float4*)&part[((size_t)b * MOM + t) * NBLK];
        float4 a0 = pr[0], a1 = pr[1], a2 = pr[2], a3 = pr[3];
#pragma unroll
        for (int u = 4; u < 16; u += 4) {
            const float4 v0 = pr[u], v1 = pr[u + 1], v2 = pr[u + 2], v3 = pr[u + 3];
            a0.x += v0.x; a0.y += v0.y; a0.z += v0.z; a0.w += v0.w;
            a1.x += v1.x; a1.y += v1.y; a1.z += v1.z; a1.w += v1.w;
            a2.x += v2.x; a2.y += v2.y; a2.z += v2.z; a2.w += v2.w;
            a3.x += v3.x; a3.y += v3.y; a3.z += v3.z; a3.w += v3.w;
        }
        const float s = ((a0.x + a0.y) + (a0.z + a0.w)) + ((a1.x + a1.y) + (a1.z + a1.w))
                      + ((a2.x + a2.y) + (a2.z + a2.w)) + ((a3.x + a3.y) + (a3.z + a3.w));
        const int k = (t < KP) ? t : ((t - KP) >> 5);
        moms[t] = s * c_invf[k];
    }
    __syncthreads();

    // per-thread Horner coefficients (pre-scaled by 1/k!)
    float Mreg[KP], Sreg[KP];
#pragma unroll
    for (int k = 0; k < KP; ++k) {
        Mreg[k] = moms[KP + k * EMB + e];
        Sreg[k] = moms[k];
    }

    // x-gen from preloaded u
#pragma unroll
    for (int q = 0; q < 8; ++q) {
        const int i = t + q * THR;
        if (i < STG * EMB) {
            const int pos = i >> 5;
            const float u = uu[q];
            const bool valid = (u >= 0.f);
            const float uc = valid ? u : 0.f;
            float num = Mreg[KP - 1], den = Sreg[KP - 1];
#pragma unroll
            for (int k = KP - 2; k >= 0; --k) {
                num = fmaf(num, uc, Mreg[k]);
                den = fmaf(den, uc, Sreg[k]);
            }
            const float rd = valid ? __builtin_amdgcn_rcpf(den) : 0.f;
            xs[e][pos] = num * rd;
        }
    }
    __syncthreads();

    const int wv = t >> 6;       // wave id 0..8
    const int lane = t & 63;

    // ---- conv1 + relu -> hs ----
    if (wv < 8) {
        const int o0 = __builtin_amdgcn_readfirstlane(wv << 2);
        const int i0 = 2 * lane;             // h idx i0+1, i0+2 (1..128)
        const float* W = w1 + o0 * 96;       // rows o0..o0+3, [o][c*3+d]
        float a[4][2];
#pragma unroll
        for (int oo = 0; oo < 4; ++oo) { const float bv = b1[o0 + oo]; a[oo][0] = bv; a[oo][1] = bv; }
#pragma unroll 4
        for (int c = 0; c < 32; ++c) {
            const float2 xa = *(const float2*)&xs[c][i0];
            const float2 xb = *(const float2*)&xs[c][i0 + 2];
#pragma unroll
            for (int oo = 0; oo < 4; ++oo) {
                const float wA = W[oo * 96 + c * 3 + 0];   // SGPR-uniform
                const float wB = W[oo * 96 + c * 3 + 1];
                const float wC = W[oo * 96 + c * 3 + 2];
                a[oo][0] = fmaf(wA, xa.x, fmaf(wB, xa.y, fmaf(wC, xb.x, a[oo][0])));
                a[oo][1] = fmaf(wA, xa.y, fmaf(wB, xb.x, fmaf(wC, xb.y, a[oo][1])));
            }
        }
        const int gp0 = start - 1 + i0;      // pos of h idx i0+1
        const bool v0 = (gp0 >= 0) && (gp0 < NPOS);
        const bool v1 = (gp0 + 1 >= 0) && (gp0 + 1 < NPOS);
#pragma unroll
        for (int oo = 0; oo < 4; ++oo) {
            float2 hv;
            hv.x = v0 ? fmaxf(a[oo][0], 0.f) : 0.f;
            hv.y = v1 ? fmaxf(a[oo][1], 0.f) : 0.f;
            *(float2*)&hs[o0 + oo][i0] = hv;
        }
    } else {
        // edge wave: h idx 129..135 for all 8 channel groups
        const int g2 = lane >> 3, p = lane & 7;
        if (p < 7) {
            const int o0e = g2 << 2;
            const int j = 129 + p;           // h idx
            float a[4];
#pragma unroll
            for (int oo = 0; oo < 4; ++oo) a[oo] = b1[o0e + oo];
#pragma unroll 4
            for (int c = 0; c < 32; ++c) {
                const float x0 = xs[c][j - 1], x1 = xs[c][j], x2 = xs[c][j + 1];
#pragma unroll
                for (int oo = 0; oo < 4; ++oo) {
                    const float wa = w1[(o0e + oo) * 96 + c * 3 + 0];
                    const float wb = w1[(o0e + oo) * 96 + c * 3 + 1];
                    const float wc = w1[(o0e + oo) * 96 + c * 3 + 2];
                    a[oo] = fmaf(wa, x0, fmaf(wb, x1, fmaf(wc, x2, a[oo])));
                }
            }
            const int gp = start - 2 + j;    // >= 127, only upper clamp needed
            const bool v = gp < NPOS;
#pragma unroll
            for (int oo = 0; oo < 4; ++oo)
                hs[o0e + oo][j - 1] = v ? fmaxf(a[oo], 0.f) : 0.f;
        }
    }
    __syncthreads();

    // ---- conv2 + residual + relu -> out ----
    if (wv < 8) {
        const int o0 = __builtin_amdgcn_readfirstlane(wv << 2);
        const int i0 = 2 * lane;             // out idx i0+2, i0+3 (2..129)
        const float* W = w2 + o0 * 96;
        float a[4][2];
#pragma unroll
        for (int oo = 0; oo < 4; ++oo) { const float bv = b2[o0 + oo]; a[oo][0] = bv; a[oo][1] = bv; }
#pragma unroll 4
        for (int c = 0; c < 32; ++c) {
            const float2 ha = *(const float2*)&hs[c][i0];
            const float2 hb = *(const float2*)&hs[c][i0 + 2];
#pragma unroll
            for (int oo = 0; oo < 4; ++oo) {
                const float wA = W[oo * 96 + c * 3 + 0];
                const float wB = W[oo * 96 + c * 3 + 1];
                const float wC = W[oo * 96 + c * 3 + 2];
                a[oo][0] = fmaf(wA, ha.x, fmaf(wB, ha.y, fmaf(wC, hb.x, a[oo][0])));
                a[oo][1] = fmaf(wA, ha.y, fmaf(wB, hb.x, fmaf(wC, hb.y, a[oo][1])));
            }
        }
        const int p0 = start + i0;           // pos of out idx i0+2
        if (p0 < NPOS) {
            const bool full = (p0 + 1 < NPOS);
#pragma unroll
            for (int oo = 0; oo < 4; ++oo) {
                const float2 xr = *(const float2*)&xs[o0 + oo][i0 + 2];
                const float r0 = fmaxf(xr.x + a[oo][0], 0.f);
                const float r1 = fmaxf(xr.y + a[oo][1], 0.f);
                float* ob = out + (size_t)(b * EMB + o0 + oo) * NPOS + p0;
                if (full) *(float2*)ob = make_float2(r0, r1);
                else ob[0] = r0;
            }
        }
    } else {
        // edge wave: out idx 130..134 for all 8 channel groups
        const int g2 = lane >> 3, p = lane & 7;
        if (p < 5) {
            const int o0e = g2 << 2;
            const int q = 130 + p;           // out idx; h taps stored at [q-2],[q-1],[q]
            float a[4];
#pragma unroll
            for (int oo = 0; oo < 4; ++oo) a[oo] = b2[o0e + oo];
#pragma unroll 4
            for (int c = 0; c < 32; ++c) {
                const float h0 = hs[c][q - 2], h1 = hs[c][q - 1], h2 = hs[c][q];
#pragma unroll
                for (int oo = 0; oo < 4; ++oo) {
                    const float wa = w2[(o0e + oo) * 96 + c * 3 + 0];
                    const float wb = w2[(o0e + oo) * 96 + c * 3 + 1];
                    const float wc = w2[(o0e + oo) * 96 + c * 3 + 2];
                    a[oo] = fmaf(wa, h0, fmaf(wb, h1, fmaf(wc, h2, a[oo])));
                }
            }
            const int pos = start + q - 2;   // start+128+p
            if (pos < NPOS) {
#pragma unroll
                for (int oo = 0; oo < 4; ++oo) {
                    const float r = fmaxf(xs[o0e + oo][q] + a[oo], 0.f);
                    out[(size_t)(b * EMB + o0e + oo) * NPOS + pos] = r;
                }
            }
        }
    }
}

extern "C" void kernel_launch(void* const* d_in, const int* in_sizes, int n_in,
                              void* d_out, int out_size, void* d_ws, size_t ws_size,
                              hipStream_t stream) {
    const float* inten = (const float*)d_in[0];
    const int* angle = (const int*)d_in[1];
    const float* emb = (const float*)d_in[2];
    const float* w1 = (const float*)d_in[3];
    const float* b1 = (const float*)d_in[4];
    const float* w2 = (const float*)d_in[5];
    const float* b2 = (const float*)d_in[6];
    float* out = (float*)d_out;
    float* part = (float*)d_ws;   // BB*528*64*4 = 540672 B

    void* kargs[] = {(void*)&inten, (void*)&angle, (void*)&emb,
                     (void*)&w1, (void*)&b1, (void*)&w2, (void*)&b2,
                     (void*)&part, (void*)&out};
    hipLaunchCooperativeKernel((const void*)fused_kernel, dim3(BB * NBLK), dim3(THR),
                               kargs, 0, stream);
}

// Round 11
// 104.694 us; speedup vs baseline: 1.1599x; 1.1599x over previous
//
#include <hip/hip_runtime.h>

#define NPOS 8500
#define BB 4
#define EMB 32
#define KP 16
#define MOM 528            /* S[16] + M[16][32] coefficients per batch */
#define NBLK 64            /* j-chunks per batch == tiles per batch */
#define JPB 133            /* j's per chunk */
#define JPS 8              /* j's per 32-lane subgroup (18 subgroups) */
#define TOUT 133           /* output positions per tile; 64*133 = 8512 */
#define STG 137            /* staged x idx [0,137): pos start-2 .. start+134 */
#define STR 138            /* LDS row stride (floats) */
#define THR 576            /* 9 waves: 8 conv waves + 1 edge wave */

__device__ __constant__ float c_invf[KP] = {
    1.f, 1.f, 0.5f, 1.f/6.f, 1.f/24.f, 1.f/120.f, 1.f/720.f, 1.f/5040.f,
    1.f/40320.f, 1.f/362880.f, 1.f/3628800.f, 1.f/39916800.f,
    1.f/479001600.f, 1.f/6227020800.f, 1.f/87178291200.f, 1.f/1307674368000.f};

// shallow power tree: p[1..15] = v^k, depth <= 4 mults; v==0 -> p[k]=0 (k>=1)
__device__ __forceinline__ void powtree(float v, float* p) {
    const float v2 = v * v;
    const float v4 = v2 * v2;
    const float v8 = v4 * v4;
    p[1] = v;          p[2] = v2;         p[3] = v2 * v;
    p[4] = v4;         p[5] = v4 * v;     p[6] = v4 * v2;
    p[7] = v4 * p[3];  p[8] = v8;         p[9] = v8 * v;
    p[10] = v8 * v2;   p[11] = v8 * p[3]; p[12] = v8 * v4;
    p[13] = v8 * p[5]; p[14] = v8 * p[6]; p[15] = v8 * p[7];
}

// ===== fused: partial moments -> per-batch arrival barrier -> reduce/x-gen/conv =====
__global__ __launch_bounds__(THR)
__attribute__((amdgpu_waves_per_eu(3, 4)))
void fused_kernel(
    const float* __restrict__ inten, const int* __restrict__ angle,
    const float* __restrict__ emb,
    const float* __restrict__ w1, const float* __restrict__ b1,
    const float* __restrict__ w2, const float* __restrict__ b2,
    float* __restrict__ part, int* __restrict__ done, float* __restrict__ out)
{
    __shared__ float moms[MOM];
    __shared__ float pool[2 * EMB * STR];   // 8832 floats; phase A overlay: red[9][528]
    float (*xs)[STR] = (float(*)[STR])pool;
    float (*hs)[STR] = (float(*)[STR])(pool + EMB * STR);
    float (*red)[MOM] = (float(*)[MOM])pool;

    const int t = threadIdx.x;
    const int b = blockIdx.x >> 6;      // 64 tiles/batch
    const int tile = blockIdx.x & 63;   // == this block's j-chunk
    const int e = t & 31;

    // ================= PHASE A: partial moments for chunk == tile =================
    {
        const int sub = t >> 5;                 // 18 subgroups of 32 lanes
        const int jlo = tile * JPB;
        const int je = min(jlo + JPB, NPOS);
        const int js = jlo + sub * JPS;

        float accM[KP], accS[KP];
#pragma unroll
        for (int k = 0; k < KP; ++k) { accM[k] = 0.f; accS[k] = 0.f; }

        const float* ib = inten + b * NPOS;
        const int* ab = angle + b * NPOS;
#pragma unroll
        for (int jj = 0; jj < JPS; ++jj) {      // fully unrolled, predicated: loads issue early
            const int j = js + jj;
            const bool valid = (j < je);
            const int jc = valid ? j : jlo;     // jlo always in-bounds
            const float v = valid ? ib[jc] * 0.01f : 0.f;
            const float evr = emb[ab[jc] * EMB + e];
            const float ev = valid ? evr : 0.f;
            float p[KP];
            powtree(v, p);
            accM[0] += ev;
            accS[0] += valid ? 1.f : 0.f;
#pragma unroll
            for (int k = 1; k < KP; ++k) {
                accM[k] = fmaf(p[k], ev, accM[k]);
                accS[k] += p[k];
            }
        }

        // fold the wave's two 32-lane subgroups (fixed order -> deterministic)
#pragma unroll
        for (int k = 0; k < KP; ++k) {
            accM[k] += __shfl_xor(accM[k], 32);
            accS[k] += __shfl_xor(accS[k], 32);
        }
        const int wv = t >> 6;
        if ((t & 32) == 0) {
#pragma unroll
            for (int k = 0; k < KP; ++k) red[wv][KP + k * EMB + e] = accM[k];
            if (e == 0) {
#pragma unroll
                for (int k = 0; k < KP; ++k) red[wv][k] = accS[k];
            }
        }
        __syncthreads();
        for (int i = t; i < MOM; i += THR) {
            float s = 0.f;
#pragma unroll
            for (int u = 0; u < 9; ++u) s += red[u][i];
            part[((size_t)b * MOM + i) * NBLK + tile] = s;
        }
    }
    __syncthreads();                            // all part writes of this block done
    if (t == 0) {
        __threadfence();                        // publish part (device scope)
        __hip_atomic_fetch_add(&done[b], 1, __ATOMIC_RELEASE, __HIP_MEMORY_SCOPE_AGENT);
    }

    // preload this thread's x-gen inputs (overlaps other blocks' phase A / our spin)
    const int start = tile * TOUT;
    float uu[8];
#pragma unroll
    for (int q = 0; q < 8; ++q) {
        const int i = t + q * THR;
        float u = -1.0f;
        if (i < STG * EMB) {
            const int pos = i >> 5;
            const int gp = start - 2 + pos;
            if (gp >= 0 && gp < NPOS) u = inten[b * NPOS + gp] * 0.01f;
        }
        uu[q] = u;
    }

    // ---- per-batch arrival barrier: wait until all 64 chunks of batch b are in ----
    if (t == 0) {
        while (__hip_atomic_load(&done[b], __ATOMIC_ACQUIRE, __HIP_MEMORY_SCOPE_AGENT) < NBLK) {
            __builtin_amdgcn_s_sleep(1);
        }
    }
    __syncthreads();
    __threadfence();                            // acquire: invalidate stale cached part lines

    // ================= PHASE B: reduce -> x(Horner) -> conv1 -> conv2 =================
    // reduce this batch's partials: one coeff per thread, 16 x float4, 4-way ILP
    if (t < MOM) {
        const float4* pr = (const float4*)&part[((size_t)b * MOM + t) * NBLK];
        float4 a0 = pr[0], a1 = pr[1], a2 = pr[2], a3 = pr[3];
#pragma unroll
        for (int u = 4; u < 16; u += 4) {
            const float4 v0 = pr[u], v1 = pr[u + 1], v2 = pr[u + 2], v3 = pr[u + 3];
            a0.x += v0.x; a0.y += v0.y; a0.z += v0.z; a0.w += v0.w;
            a1.x += v1.x; a1.y += v1.y; a1.z += v1.z; a1.w += v1.w;
            a2.x += v2.x; a2.y += v2.y; a2.z += v2.z; a2.w += v2.w;
            a3.x += v3.x; a3.y += v3.y; a3.z += v3.z; a3.w += v3.w;
        }
        const float s = ((a0.x + a0.y) + (a0.z + a0.w)) + ((a1.x + a1.y) + (a1.z + a1.w))
                      + ((a2.x + a2.y) + (a2.z + a2.w)) + ((a3.x + a3.y) + (a3.z + a3.w));
        const int k = (t < KP) ? t : ((t - KP) >> 5);
        moms[t] = s * c_invf[k];
    }
    __syncthreads();

    // per-thread Horner coefficients (pre-scaled by 1/k!)
    float Mreg[KP], Sreg[KP];
#pragma unroll
    for (int k = 0; k < KP; ++k) {
        Mreg[k] = moms[KP + k * EMB + e];
        Sreg[k] = moms[k];
    }

    // x-gen from preloaded u
#pragma unroll
    for (int q = 0; q < 8; ++q) {
        const int i = t + q * THR;
        if (i < STG * EMB) {
            const int pos = i >> 5;
            const float u = uu[q];
            const bool valid = (u >= 0.f);
            const float uc = valid ? u : 0.f;
            float num = Mreg[KP - 1], den = Sreg[KP - 1];
#pragma unroll
            for (int k = KP - 2; k >= 0; --k) {
                num = fmaf(num, uc, Mreg[k]);
                den = fmaf(den, uc, Sreg[k]);
            }
            const float rd = valid ? __builtin_amdgcn_rcpf(den) : 0.f;
            xs[e][pos] = num * rd;
        }
    }
    __syncthreads();

    const int wv = t >> 6;       // wave id 0..8
    const int lane = t & 63;

    // ---- conv1 + relu -> hs ----
    if (wv < 8) {
        const int o0 = __builtin_amdgcn_readfirstlane(wv << 2);
        const int i0 = 2 * lane;             // h idx i0+1, i0+2 (1..128)
        const float* W = w1 + o0 * 96;       // rows o0..o0+3, [o][c*3+d]
        float a[4][2];
#pragma unroll
        for (int oo = 0; oo < 4; ++oo) { const float bv = b1[o0 + oo]; a[oo][0] = bv; a[oo][1] = bv; }
#pragma unroll 4
        for (int c = 0; c < 32; ++c) {
            const float2 xa = *(const float2*)&xs[c][i0];
            const float2 xb = *(const float2*)&xs[c][i0 + 2];
#pragma unroll
            for (int oo = 0; oo < 4; ++oo) {
                const float wA = W[oo * 96 + c * 3 + 0];   // SGPR-uniform
                const float wB = W[oo * 96 + c * 3 + 1];
                const float wC = W[oo * 96 + c * 3 + 2];
                a[oo][0] = fmaf(wA, xa.x, fmaf(wB, xa.y, fmaf(wC, xb.x, a[oo][0])));
                a[oo][1] = fmaf(wA, xa.y, fmaf(wB, xb.x, fmaf(wC, xb.y, a[oo][1])));
            }
        }
        const int gp0 = start - 1 + i0;      // pos of h idx i0+1
        const bool v0 = (gp0 >= 0) && (gp0 < NPOS);
        const bool v1 = (gp0 + 1 >= 0) && (gp0 + 1 < NPOS);
#pragma unroll
        for (int oo = 0; oo < 4; ++oo) {
            float2 hv;
            hv.x = v0 ? fmaxf(a[oo][0], 0.f) : 0.f;
            hv.y = v1 ? fmaxf(a[oo][1], 0.f) : 0.f;
            *(float2*)&hs[o0 + oo][i0] = hv;
        }
    } else {
        // edge wave: h idx 129..135 for all 8 channel groups
        const int g2 = lane >> 3, p = lane & 7;
        if (p < 7) {
            const int o0e = g2 << 2;
            const int j = 129 + p;           // h idx
            float a[4];
#pragma unroll
            for (int oo = 0; oo < 4; ++oo) a[oo] = b1[o0e + oo];
#pragma unroll 4
            for (int c = 0; c < 32; ++c) {
                const float x0 = xs[c][j - 1], x1 = xs[c][j], x2 = xs[c][j + 1];
#pragma unroll
                for (int oo = 0; oo < 4; ++oo) {
                    const float wa = w1[(o0e + oo) * 96 + c * 3 + 0];
                    const float wb = w1[(o0e + oo) * 96 + c * 3 + 1];
                    const float wc = w1[(o0e + oo) * 96 + c * 3 + 2];
                    a[oo] = fmaf(wa, x0, fmaf(wb, x1, fmaf(wc, x2, a[oo])));
                }
            }
            const int gp = start - 2 + j;    // >= 127, only upper clamp needed
            const bool v = gp < NPOS;
#pragma unroll
            for (int oo = 0; oo < 4; ++oo)
                hs[o0e + oo][j - 1] = v ? fmaxf(a[oo], 0.f) : 0.f;
        }
    }
    __syncthreads();

    // ---- conv2 + residual + relu -> out ----
    if (wv < 8) {
        const int o0 = __builtin_amdgcn_readfirstlane(wv << 2);
        const int i0 = 2 * lane;             // out idx i0+2, i0+3 (2..129)
        const float* W = w2 + o0 * 96;
        float a[4][2];
#pragma unroll
        for (int oo = 0; oo < 4; ++oo) { const float bv = b2[o0 + oo]; a[oo][0] = bv; a[oo][1] = bv; }
#pragma unroll 4
        for (int c = 0; c < 32; ++c) {
            const float2 ha = *(const float2*)&hs[c][i0];
            const float2 hb = *(const float2*)&hs[c][i0 + 2];
#pragma unroll
            for (int oo = 0; oo < 4; ++oo) {
                const float wA = W[oo * 96 + c * 3 + 0];
                const float wB = W[oo * 96 + c * 3 + 1];
                const float wC = W[oo * 96 + c * 3 + 2];
                a[oo][0] = fmaf(wA, ha.x, fmaf(wB, ha.y, fmaf(wC, hb.x, a[oo][0])));
                a[oo][1] = fmaf(wA, ha.y, fmaf(wB, hb.x, fmaf(wC, hb.y, a[oo][1])));
            }
        }
        const int p0 = start + i0;           // pos of out idx i0+2
        if (p0 < NPOS) {
            const bool full = (p0 + 1 < NPOS);
#pragma unroll
            for (int oo = 0; oo < 4; ++oo) {
                const float2 xr = *(const float2*)&xs[o0 + oo][i0 + 2];
                const float r0 = fmaxf(xr.x + a[oo][0], 0.f);
                const float r1 = fmaxf(xr.y + a[oo][1], 0.f);
                float* ob = out + (size_t)(b * EMB + o0 + oo) * NPOS + p0;
                if (full) *(float2*)ob = make_float2(r0, r1);
                else ob[0] = r0;
            }
        }
    } else {
        // edge wave: out idx 130..134 for all 8 channel groups
        const int g2 = lane >> 3, p = lane & 7;
        if (p < 5) {
            const int o0e = g2 << 2;
            const int q = 130 + p;           // out idx; h taps stored at [q-2],[q-1],[q]
            float a[4];
#pragma unroll
            for (int oo = 0; oo < 4; ++oo) a[oo] = b2[o0e + oo];
#pragma unroll 4
            for (int c = 0; c < 32; ++c) {
                const float h0 = hs[c][q - 2], h1 = hs[c][q - 1], h2 = hs[c][q];
#pragma unroll
                for (int oo = 0; oo < 4; ++oo) {
                    const float wa = w2[(o0e + oo) * 96 + c * 3 + 0];
                    const float wb = w2[(o0e + oo) * 96 + c * 3 + 1];
                    const float wc = w2[(o0e + oo) * 96 + c * 3 + 2];
                    a[oo] = fmaf(wa, h0, fmaf(wb, h1, fmaf(wc, h2, a[oo])));
                }
            }
            const int pos = start + q - 2;   // start+128+p
            if (pos < NPOS) {
#pragma unroll
                for (int oo = 0; oo < 4; ++oo) {
                    const float r = fmaxf(xs[o0e + oo][q] + a[oo], 0.f);
                    out[(size_t)(b * EMB + o0e + oo) * NPOS + pos] = r;
                }
            }
        }
    }
}

extern "C" void kernel_launch(void* const* d_in, const int* in_sizes, int n_in,
                              void* d_out, int out_size, void* d_ws, size_t ws_size,
                              hipStream_t stream) {
    const float* inten = (const float*)d_in[0];
    const int* angle = (const int*)d_in[1];
    const float* emb = (const float*)d_in[2];
    const float* w1 = (const float*)d_in[3];
    const float* b1 = (const float*)d_in[4];
    const float* w2 = (const float*)d_in[5];
    const float* b2 = (const float*)d_in[6];
    float* out = (float*)d_out;

    float* part = (float*)d_ws;                                        // 540672 B
    int* done = (int*)((char*)d_ws + (size_t)BB * MOM * NBLK * 4);     // 4 ints

    hipMemsetAsync(done, 0, BB * sizeof(int), stream);   // reset barrier each call

    void* kargs[] = {(void*)&inten, (void*)&angle, (void*)&emb,
                     (void*)&w1, (void*)&b1, (void*)&w2, (void*)&b2,
                     (void*)&part, (void*)&done, (void*)&out};
    hipLaunchCooperativeKernel((const void*)fused_kernel, dim3(BB * NBLK), dim3(THR),
                               kargs, 0, stream);
}

// Round 12
// 24.755 us; speedup vs baseline: 4.9055x; 4.2291x over previous
//
#include <hip/hip_runtime.h>

#define NPOS 8500
#define BB 4
#define EMB 32
#define KP 16
#define MOM 528            /* S[16] + M[16][32] coefficients per batch */
#define NBLK 64            /* j-chunks per batch in k1 */
#define JPB 133            /* j's per chunk */
#define JPS 9              /* j's per 32-lane subgroup (16 subgroups) */
#define TOUT 133           /* output positions per tile; 64*133 = 8512 */
#define NT 64              /* tiles per batch -> grid = 256 exactly */
#define STG 137            /* staged x idx [0,137): pos start-2 .. start+134 */
#define STR 138            /* LDS row stride (floats), rows 8B-aligned */
#define THR 576            /* 9 waves: 8 conv waves + 1 edge wave */

__device__ __constant__ float c_invf[KP] = {
    1.f, 1.f, 0.5f, 1.f/6.f, 1.f/24.f, 1.f/120.f, 1.f/720.f, 1.f/5040.f,
    1.f/40320.f, 1.f/362880.f, 1.f/3628800.f, 1.f/39916800.f,
    1.f/479001600.f, 1.f/6227020800.f, 1.f/87178291200.f, 1.f/1307674368000.f};

// shallow power tree: p[1..15] = v^k, depth <= 4 mults
__device__ __forceinline__ void powtree(float v, float* p) {
    const float v2 = v * v;
    const float v4 = v2 * v2;
    const float v8 = v4 * v4;
    p[1] = v;          p[2] = v2;         p[3] = v2 * v;
    p[4] = v4;         p[5] = v4 * v;     p[6] = v4 * v2;
    p[7] = v4 * p[3];  p[8] = v8;         p[9] = v8 * v;
    p[10] = v8 * v2;   p[11] = v8 * p[3]; p[12] = v8 * v4;
    p[13] = v8 * p[5]; p[14] = v8 * p[6]; p[15] = v8 * p[7];
}

// ---------------- kernel 1: partial moments (fixed order), grid = 256 exactly ----------------
// part layout: part[(b*MOM + i)*NBLK + blk]  (blk contiguous -> float4 reduce in main)
__global__ __launch_bounds__(512) void moments_partial(
    const float* __restrict__ inten, const int* __restrict__ angle,
    const float* __restrict__ emb, float* __restrict__ part)
{
    const int b = blockIdx.x >> 6;
    const int blk = blockIdx.x & 63;
    const int t = threadIdx.x;
    const int sub = t >> 5;                     // 16 subgroups of 32 lanes
    const int e = t & 31;                       // embed lane
    const int jlo = blk * JPB;
    const int jhi = min(jlo + JPB, NPOS);
    const int js = jlo + sub * JPS;
    const int je = min(js + JPS, jhi);

    float accM[KP], accS[KP];
#pragma unroll
    for (int k = 0; k < KP; ++k) { accM[k] = 0.f; accS[k] = 0.f; }

    const float* ib = inten + b * NPOS;
    const int* ab = angle + b * NPOS;
    int j = js;
    for (; j + 1 < je; j += 2) {                // two independent power chains
        const float va = ib[j] * 0.01f;
        const float vb = ib[j + 1] * 0.01f;
        const float eva = emb[ab[j] * EMB + e];
        const float evb = emb[ab[j + 1] * EMB + e];
        float pa[KP], pb[KP];
        powtree(va, pa);
        powtree(vb, pb);
        accM[0] += eva + evb;
        accS[0] += 2.0f;
#pragma unroll
        for (int k = 1; k < KP; ++k) {
            accM[k] = fmaf(pa[k], eva, accM[k]);
            accM[k] = fmaf(pb[k], evb, accM[k]);
            accS[k] += pa[k] + pb[k];
        }
    }
    if (j < je) {
        const float v = ib[j] * 0.01f;
        const float ev = emb[ab[j] * EMB + e];
        float p[KP];
        powtree(v, p);
        accM[0] += ev;
        accS[0] += 1.0f;
#pragma unroll
        for (int k = 1; k < KP; ++k) {
            accM[k] = fmaf(p[k], ev, accM[k]);
            accS[k] += p[k];
        }
    }

    // fold subgroup pairs within each wave (fixed order -> deterministic)
#pragma unroll
    for (int k = 0; k < KP; ++k) {
        accM[k] += __shfl_xor(accM[k], 32);
        accS[k] += __shfl_xor(accS[k], 32);
    }
    __shared__ float red[8][MOM];
    const int wv = t >> 6;
    if ((t & 32) == 0) {
#pragma unroll
        for (int k = 0; k < KP; ++k) red[wv][KP + k * EMB + e] = accM[k];
        if (e == 0) {
#pragma unroll
            for (int k = 0; k < KP; ++k) red[wv][k] = accS[k];
        }
    }
    __syncthreads();
    for (int i = t; i < MOM; i += 512) {
        float s = 0.f;
#pragma unroll
        for (int u = 0; u < 8; ++u) s += red[u][i];
        part[((size_t)b * MOM + i) * NBLK + blk] = s;
    }
}

// ---------------- kernel 2: reduce + x(Horner) -> conv1+relu -> conv2+res+relu ----------------
// Weights/biases via wave-uniform scalar loads from ORIGINAL layout (no transpose, no LDS).
__global__ __launch_bounds__(THR) void main_kernel(
    const float* __restrict__ inten, const float* __restrict__ part,
    const float* __restrict__ w1, const float* __restrict__ b1,
    const float* __restrict__ w2, const float* __restrict__ b2,
    float* __restrict__ out)
{
    __shared__ float moms[MOM];
    __shared__ float redq[4][MOM];  // quarter partials of the part-reduce
    __shared__ float xs[EMB][STR];  // x idx 0..136 (pos = start-2+idx)
    __shared__ float hs[EMB][STR];  // h idx j stored at [j-1], j in 1..135

    const int t = threadIdx.x;
    const int b = blockIdx.x >> 6;      // NT = 64
    const int tile = blockIdx.x & 63;
    const int start = tile * TOUT;
    const int e = t & 31;

    // ---- preload this thread's x-gen inputs (u<0 == invalid sentinel) ----
    float uu[8];
#pragma unroll
    for (int q = 0; q < 8; ++q) {
        const int i = t + q * THR;
        float u = -1.0f;
        if (i < STG * EMB) {
            const int pos = i >> 5;
            const int gp = start - 2 + pos;
            if (gp >= 0 && gp < NPOS) u = inten[b * NPOS + gp] * 0.01f;
        }
        uu[q] = u;
    }

    // ---- reduce this batch's partials: 2112 independent (coeff, quarter) items ----
    // item m: coeff i = m>>2, quarter q = m&3 -> sums part[...][q*16 .. q*16+15]
#pragma unroll
    for (int mq = 0; mq < 4; ++mq) {
        const int m = t + mq * THR;
        if (m < 4 * MOM) {
            const int i = m >> 2, q = m & 3;
            const float4* pr = (const float4*)&part[((size_t)b * MOM + i) * NBLK + q * 16];
            const float4 s0 = pr[0], s1 = pr[1], s2 = pr[2], s3 = pr[3];
            float4 sa;
            sa.x = (s0.x + s1.x) + (s2.x + s3.x);
            sa.y = (s0.y + s1.y) + (s2.y + s3.y);
            sa.z = (s0.z + s1.z) + (s2.z + s3.z);
            sa.w = (s0.w + s1.w) + (s2.w + s3.w);
            redq[q][i] = (sa.x + sa.y) + (sa.z + sa.w);
        }
    }
    __syncthreads();
    if (t < MOM) {
        const float s = (redq[0][t] + redq[1][t]) + (redq[2][t] + redq[3][t]);
        const int k = (t < KP) ? t : ((t - KP) >> 5);
        moms[t] = s * c_invf[k];
    }
    __syncthreads();

    // per-thread Horner coefficients (pre-scaled by 1/k!)
    float Mreg[KP], Sreg[KP];
#pragma unroll
    for (int k = 0; k < KP; ++k) {
        Mreg[k] = moms[KP + k * EMB + e];
        Sreg[k] = moms[k];
    }

    // ---- x-gen from preloaded u ----
#pragma unroll
    for (int q = 0; q < 8; ++q) {
        const int i = t + q * THR;
        if (i < STG * EMB) {
            const int pos = i >> 5;
            const float u = uu[q];
            const bool valid = (u >= 0.f);
            const float uc = valid ? u : 0.f;
            float num = Mreg[KP - 1], den = Sreg[KP - 1];
#pragma unroll
            for (int k = KP - 2; k >= 0; --k) {
                num = fmaf(num, uc, Mreg[k]);
                den = fmaf(den, uc, Sreg[k]);
            }
            const float rd = valid ? __builtin_amdgcn_rcpf(den) : 0.f;
            xs[e][pos] = num * rd;
        }
    }
    __syncthreads();

    const int wv = t >> 6;       // wave id 0..8
    const int lane = t & 63;

    // ---- conv1 + relu -> hs ----
    if (wv < 8) {
        const int o0 = __builtin_amdgcn_readfirstlane(wv << 2);
        const int i0 = 2 * lane;             // h idx i0+1, i0+2 (1..128)
        const float* W = w1 + o0 * 96;       // rows o0..o0+3, [o][c*3+d]
        float a[4][2];
#pragma unroll
        for (int oo = 0; oo < 4; ++oo) { const float bv = b1[o0 + oo]; a[oo][0] = bv; a[oo][1] = bv; }
#pragma unroll 4
        for (int c = 0; c < 32; ++c) {
            const float2 xa = *(const float2*)&xs[c][i0];
            const float2 xb = *(const float2*)&xs[c][i0 + 2];
#pragma unroll
            for (int oo = 0; oo < 4; ++oo) {
                const float wA = W[oo * 96 + c * 3 + 0];   // SGPR-uniform
                const float wB = W[oo * 96 + c * 3 + 1];
                const float wC = W[oo * 96 + c * 3 + 2];
                a[oo][0] = fmaf(wA, xa.x, fmaf(wB, xa.y, fmaf(wC, xb.x, a[oo][0])));
                a[oo][1] = fmaf(wA, xa.y, fmaf(wB, xb.x, fmaf(wC, xb.y, a[oo][1])));
            }
        }
        const int gp0 = start - 1 + i0;      // pos of h idx i0+1
        const bool v0 = (gp0 >= 0) && (gp0 < NPOS);
        const bool v1 = (gp0 + 1 >= 0) && (gp0 + 1 < NPOS);
#pragma unroll
        for (int oo = 0; oo < 4; ++oo) {
            float2 hv;
            hv.x = v0 ? fmaxf(a[oo][0], 0.f) : 0.f;
            hv.y = v1 ? fmaxf(a[oo][1], 0.f) : 0.f;
            *(float2*)&hs[o0 + oo][i0] = hv;
        }
    } else {
        // edge wave: h idx 129..135 for all 8 channel groups
        const int g2 = lane >> 3, p = lane & 7;
        if (p < 7) {
            const int o0e = g2 << 2;
            const int j = 129 + p;           // h idx
            float a[4];
#pragma unroll
            for (int oo = 0; oo < 4; ++oo) a[oo] = b1[o0e + oo];
#pragma unroll 4
            for (int c = 0; c < 32; ++c) {
                const float x0 = xs[c][j - 1], x1 = xs[c][j], x2 = xs[c][j + 1];
#pragma unroll
                for (int oo = 0; oo < 4; ++oo) {
                    const float wa = w1[(o0e + oo) * 96 + c * 3 + 0];
                    const float wb = w1[(o0e + oo) * 96 + c * 3 + 1];
                    const float wc = w1[(o0e + oo) * 96 + c * 3 + 2];
                    a[oo] = fmaf(wa, x0, fmaf(wb, x1, fmaf(wc, x2, a[oo])));
                }
            }
            const int gp = start - 2 + j;    // >= 127, only upper clamp needed
            const bool v = gp < NPOS;
#pragma unroll
            for (int oo = 0; oo < 4; ++oo)
                hs[o0e + oo][j - 1] = v ? fmaxf(a[oo], 0.f) : 0.f;
        }
    }
    __syncthreads();

    // ---- conv2 + residual + relu -> out ----
    if (wv < 8) {
        const int o0 = __builtin_amdgcn_readfirstlane(wv << 2);
        const int i0 = 2 * lane;             // out idx i0+2, i0+3 (2..129)
        const float* W = w2 + o0 * 96;
        float a[4][2];
#pragma unroll
        for (int oo = 0; oo < 4; ++oo) { const float bv = b2[o0 + oo]; a[oo][0] = bv; a[oo][1] = bv; }
#pragma unroll 4
        for (int c = 0; c < 32; ++c) {
            const float2 ha = *(const float2*)&hs[c][i0];
            const float2 hb = *(const float2*)&hs[c][i0 + 2];
#pragma unroll
            for (int oo = 0; oo < 4; ++oo) {
                const float wA = W[oo * 96 + c * 3 + 0];
                const float wB = W[oo * 96 + c * 3 + 1];
                const float wC = W[oo * 96 + c * 3 + 2];
                a[oo][0] = fmaf(wA, ha.x, fmaf(wB, ha.y, fmaf(wC, hb.x, a[oo][0])));
                a[oo][1] = fmaf(wA, ha.y, fmaf(wB, hb.x, fmaf(wC, hb.y, a[oo][1])));
            }
        }
        const int p0 = start + i0;           // pos of out idx i0+2
        if (p0 < NPOS) {
            const bool full = (p0 + 1 < NPOS);
#pragma unroll
            for (int oo = 0; oo < 4; ++oo) {
                const float2 xr = *(const float2*)&xs[o0 + oo][i0 + 2];
                const float r0 = fmaxf(xr.x + a[oo][0], 0.f);
                const float r1 = fmaxf(xr.y + a[oo][1], 0.f);
                float* ob = out + (size_t)(b * EMB + o0 + oo) * NPOS + p0;
                if (full) *(float2*)ob = make_float2(r0, r1);
                else ob[0] = r0;
            }
        }
    } else {
        // edge wave: out idx 130..134 for all 8 channel groups
        const int g2 = lane >> 3, p = lane & 7;
        if (p < 5) {
            const int o0e = g2 << 2;
            const int q = 130 + p;           // out idx; h taps stored at [q-2],[q-1],[q]
            float a[4];
#pragma unroll
            for (int oo = 0; oo < 4; ++oo) a[oo] = b2[o0e + oo];
#pragma unroll 4
            for (int c = 0; c < 32; ++c) {
                const float h0 = hs[c][q - 2], h1 = hs[c][q - 1], h2 = hs[c][q];
#pragma unroll
                for (int oo = 0; oo < 4; ++oo) {
                    const float wa = w2[(o0e + oo) * 96 + c * 3 + 0];
                    const float wb = w2[(o0e + oo) * 96 + c * 3 + 1];
                    const float wc = w2[(o0e + oo) * 96 + c * 3 + 2];
                    a[oo] = fmaf(wa, h0, fmaf(wb, h1, fmaf(wc, h2, a[oo])));
                }
            }
            const int pos = start + q - 2;   // start+128+p
            if (pos < NPOS) {
#pragma unroll
                for (int oo = 0; oo < 4; ++oo) {
                    const float r = fmaxf(xs[o0e + oo][q] + a[oo], 0.f);
                    out[(size_t)(b * EMB + o0e + oo) * NPOS + pos] = r;
                }
            }
        }
    }
}

extern "C" void kernel_launch(void* const* d_in, const int* in_sizes, int n_in,
                              void* d_out, int out_size, void* d_ws, size_t ws_size,
                              hipStream_t stream) {
    const float* inten = (const float*)d_in[0];
    const int* angle = (const int*)d_in[1];
    const float* emb = (const float*)d_in[2];
    const float* w1 = (const float*)d_in[3];
    const float* b1 = (const float*)d_in[4];
    const float* w2 = (const float*)d_in[5];
    const float* b2 = (const float*)d_in[6];
    float* out = (float*)d_out;

    float* part = (float*)d_ws;   // BB*528*64*4 = 540672 B

    moments_partial<<<BB * NBLK, 512, 0, stream>>>(inten, angle, emb, part);
    main_kernel<<<BB * NT, THR, 0, stream>>>(inten, part, w1, b1, w2, b2, out);
}

// Round 13
// 23.423 us; speedup vs baseline: 5.1845x; 1.0569x over previous
//
#include <hip/hip_runtime.h>

#define NPOS 8500
#define BB 4
#define EMB 32
#define KP 12              /* Taylor terms: truncation rel err <= e/12! ~ 2.3e-9 */
#define MOM (KP + KP * EMB) /* 396: S[12] + M[12][32] per batch */
#define NBLK 64            /* j-chunks per batch in k1 */
#define JPB 133            /* j's per chunk */
#define JPS 9              /* j's per 32-lane subgroup (16 subgroups) */
#define TOUT 133           /* output positions per tile; 64*133 = 8512 */
#define NT 64              /* tiles per batch -> grid = 256 exactly */
#define STG 137            /* staged x idx [0,137): pos start-2 .. start+134 */
#define STR 138            /* LDS row stride (floats), rows 8B-aligned */
#define THR 576            /* 9 waves: 8 conv waves + 1 edge wave */

__device__ __constant__ float c_invf[KP] = {
    1.f, 1.f, 0.5f, 1.f/6.f, 1.f/24.f, 1.f/120.f, 1.f/720.f, 1.f/5040.f,
    1.f/40320.f, 1.f/362880.f, 1.f/3628800.f, 1.f/39916800.f};

// shallow power tree: p[1..11] = v^k, depth <= 4 mults
__device__ __forceinline__ void powtree(float v, float* p) {
    const float v2 = v * v;
    const float v4 = v2 * v2;
    const float v8 = v4 * v4;
    p[1] = v;          p[2] = v2;         p[3] = v2 * v;
    p[4] = v4;         p[5] = v4 * v;     p[6] = v4 * v2;
    p[7] = v4 * p[3];  p[8] = v8;         p[9] = v8 * v;
    p[10] = v8 * v2;   p[11] = v8 * p[3];
}

// ---------------- kernel 1: partial moments (fixed order), grid = 256 exactly ----------------
// part layout: part[(b*MOM + i)*NBLK + blk]  (blk contiguous -> float4 reduce in main)
__global__ __launch_bounds__(512) void moments_partial(
    const float* __restrict__ inten, const int* __restrict__ angle,
    const float* __restrict__ emb, float* __restrict__ part)
{
    const int b = blockIdx.x >> 6;
    const int blk = blockIdx.x & 63;
    const int t = threadIdx.x;
    const int sub = t >> 5;                     // 16 subgroups of 32 lanes
    const int e = t & 31;                       // embed lane
    const int jlo = blk * JPB;
    const int jhi = min(jlo + JPB, NPOS);
    const int js = jlo + sub * JPS;
    const int je = min(js + JPS, jhi);

    float accM[KP], accS[KP];
#pragma unroll
    for (int k = 0; k < KP; ++k) { accM[k] = 0.f; accS[k] = 0.f; }

    const float* ib = inten + b * NPOS;
    const int* ab = angle + b * NPOS;
    int j = js;
    for (; j + 1 < je; j += 2) {                // two independent power chains
        const float va = ib[j] * 0.01f;
        const float vb = ib[j + 1] * 0.01f;
        const float eva = emb[ab[j] * EMB + e];
        const float evb = emb[ab[j + 1] * EMB + e];
        float pa[KP], pb[KP];
        powtree(va, pa);
        powtree(vb, pb);
        accM[0] += eva + evb;
        accS[0] += 2.0f;
#pragma unroll
        for (int k = 1; k < KP; ++k) {
            accM[k] = fmaf(pa[k], eva, accM[k]);
            accM[k] = fmaf(pb[k], evb, accM[k]);
            accS[k] += pa[k] + pb[k];
        }
    }
    if (j < je) {
        const float v = ib[j] * 0.01f;
        const float ev = emb[ab[j] * EMB + e];
        float p[KP];
        powtree(v, p);
        accM[0] += ev;
        accS[0] += 1.0f;
#pragma unroll
        for (int k = 1; k < KP; ++k) {
            accM[k] = fmaf(p[k], ev, accM[k]);
            accS[k] += p[k];
        }
    }

    // fold subgroup pairs within each wave (fixed order -> deterministic)
#pragma unroll
    for (int k = 0; k < KP; ++k) {
        accM[k] += __shfl_xor(accM[k], 32);
        accS[k] += __shfl_xor(accS[k], 32);
    }
    __shared__ float red[8][MOM];
    const int wv = t >> 6;
    if ((t & 32) == 0) {
#pragma unroll
        for (int k = 0; k < KP; ++k) red[wv][KP + k * EMB + e] = accM[k];
        if (e == 0) {
#pragma unroll
            for (int k = 0; k < KP; ++k) red[wv][k] = accS[k];
        }
    }
    __syncthreads();
    for (int i = t; i < MOM; i += 512) {
        float s = 0.f;
#pragma unroll
        for (int u = 0; u < 8; ++u) s += red[u][i];
        part[((size_t)b * MOM + i) * NBLK + blk] = s;
    }
}

// ---------------- kernel 2: reduce + x(Horner) -> conv1+relu -> conv2+res+relu ----------------
// Weights/biases via wave-uniform scalar loads from ORIGINAL layout (no transpose, no LDS).
__global__ __launch_bounds__(THR) void main_kernel(
    const float* __restrict__ inten, const float* __restrict__ part,
    const float* __restrict__ w1, const float* __restrict__ b1,
    const float* __restrict__ w2, const float* __restrict__ b2,
    float* __restrict__ out)
{
    __shared__ float moms[MOM];
    __shared__ float redq[4][MOM];  // quarter partials of the part-reduce
    __shared__ float xs[EMB][STR];  // x idx 0..136 (pos = start-2+idx)
    __shared__ float hs[EMB][STR];  // h idx j stored at [j-1], j in 1..135

    const int t = threadIdx.x;
    const int b = blockIdx.x >> 6;      // NT = 64
    const int tile = blockIdx.x & 63;
    const int start = tile * TOUT;
    const int e = t & 31;

    // ---- preload this thread's x-gen inputs (u<0 == invalid sentinel) ----
    float uu[8];
#pragma unroll
    for (int q = 0; q < 8; ++q) {
        const int i = t + q * THR;
        float u = -1.0f;
        if (i < STG * EMB) {
            const int pos = i >> 5;
            const int gp = start - 2 + pos;
            if (gp >= 0 && gp < NPOS) u = inten[b * NPOS + gp] * 0.01f;
        }
        uu[q] = u;
    }

    // ---- reduce this batch's partials: 1584 independent (coeff, quarter) items ----
    // item m: coeff i = m>>2, quarter q = m&3 -> sums part[...][q*16 .. q*16+15]
#pragma unroll
    for (int mq = 0; mq < 3; ++mq) {
        const int m = t + mq * THR;
        if (m < 4 * MOM) {
            const int i = m >> 2, q = m & 3;
            const float4* pr = (const float4*)&part[((size_t)b * MOM + i) * NBLK + q * 16];
            const float4 s0 = pr[0], s1 = pr[1], s2 = pr[2], s3 = pr[3];
            float4 sa;
            sa.x = (s0.x + s1.x) + (s2.x + s3.x);
            sa.y = (s0.y + s1.y) + (s2.y + s3.y);
            sa.z = (s0.z + s1.z) + (s2.z + s3.z);
            sa.w = (s0.w + s1.w) + (s2.w + s3.w);
            redq[q][i] = (sa.x + sa.y) + (sa.z + sa.w);
        }
    }
    __syncthreads();
    if (t < MOM) {
        const float s = (redq[0][t] + redq[1][t]) + (redq[2][t] + redq[3][t]);
        const int k = (t < KP) ? t : ((t - KP) >> 5);
        moms[t] = s * c_invf[k];
    }
    __syncthreads();

    // per-thread Horner coefficients (pre-scaled by 1/k!)
    float Mreg[KP], Sreg[KP];
#pragma unroll
    for (int k = 0; k < KP; ++k) {
        Mreg[k] = moms[KP + k * EMB + e];
        Sreg[k] = moms[k];
    }

    // ---- x-gen from preloaded u ----
#pragma unroll
    for (int q = 0; q < 8; ++q) {
        const int i = t + q * THR;
        if (i < STG * EMB) {
            const int pos = i >> 5;
            const float u = uu[q];
            const bool valid = (u >= 0.f);
            const float uc = valid ? u : 0.f;
            float num = Mreg[KP - 1], den = Sreg[KP - 1];
#pragma unroll
            for (int k = KP - 2; k >= 0; --k) {
                num = fmaf(num, uc, Mreg[k]);
                den = fmaf(den, uc, Sreg[k]);
            }
            const float rd = valid ? __builtin_amdgcn_rcpf(den) : 0.f;
            xs[e][pos] = num * rd;
        }
    }
    __syncthreads();

    const int wv = t >> 6;       // wave id 0..8
    const int lane = t & 63;

    // ---- conv1 + relu -> hs ----
    if (wv < 8) {
        const int o0 = __builtin_amdgcn_readfirstlane(wv << 2);
        const int i0 = 2 * lane;             // h idx i0+1, i0+2 (1..128)
        const float* W = w1 + o0 * 96;       // rows o0..o0+3, [o][c*3+d]
        float a[4][2];
#pragma unroll
        for (int oo = 0; oo < 4; ++oo) { const float bv = b1[o0 + oo]; a[oo][0] = bv; a[oo][1] = bv; }
#pragma unroll 4
        for (int c = 0; c < 32; ++c) {
            const float2 xa = *(const float2*)&xs[c][i0];
            const float2 xb = *(const float2*)&xs[c][i0 + 2];
#pragma unroll
            for (int oo = 0; oo < 4; ++oo) {
                const float wA = W[oo * 96 + c * 3 + 0];   // SGPR-uniform
                const float wB = W[oo * 96 + c * 3 + 1];
                const float wC = W[oo * 96 + c * 3 + 2];
                a[oo][0] = fmaf(wA, xa.x, fmaf(wB, xa.y, fmaf(wC, xb.x, a[oo][0])));
                a[oo][1] = fmaf(wA, xa.y, fmaf(wB, xb.x, fmaf(wC, xb.y, a[oo][1])));
            }
        }
        const int gp0 = start - 1 + i0;      // pos of h idx i0+1
        const bool v0 = (gp0 >= 0) && (gp0 < NPOS);
        const bool v1 = (gp0 + 1 >= 0) && (gp0 + 1 < NPOS);
#pragma unroll
        for (int oo = 0; oo < 4; ++oo) {
            float2 hv;
            hv.x = v0 ? fmaxf(a[oo][0], 0.f) : 0.f;
            hv.y = v1 ? fmaxf(a[oo][1], 0.f) : 0.f;
            *(float2*)&hs[o0 + oo][i0] = hv;
        }
    } else {
        // edge wave: h idx 129..135 for all 8 channel groups
        const int g2 = lane >> 3, p = lane & 7;
        if (p < 7) {
            const int o0e = g2 << 2;
            const int j = 129 + p;           // h idx
            float a[4];
#pragma unroll
            for (int oo = 0; oo < 4; ++oo) a[oo] = b1[o0e + oo];
#pragma unroll 4
            for (int c = 0; c < 32; ++c) {
                const float x0 = xs[c][j - 1], x1 = xs[c][j], x2 = xs[c][j + 1];
#pragma unroll
                for (int oo = 0; oo < 4; ++oo) {
                    const float wa = w1[(o0e + oo) * 96 + c * 3 + 0];
                    const float wb = w1[(o0e + oo) * 96 + c * 3 + 1];
                    const float wc = w1[(o0e + oo) * 96 + c * 3 + 2];
                    a[oo] = fmaf(wa, x0, fmaf(wb, x1, fmaf(wc, x2, a[oo])));
                }
            }
            const int gp = start - 2 + j;    // >= 127, only upper clamp needed
            const bool v = gp < NPOS;
#pragma unroll
            for (int oo = 0; oo < 4; ++oo)
                hs[o0e + oo][j - 1] = v ? fmaxf(a[oo], 0.f) : 0.f;
        }
    }
    __syncthreads();

    // ---- conv2 + residual + relu -> out ----
    if (wv < 8) {
        const int o0 = __builtin_amdgcn_readfirstlane(wv << 2);
        const int i0 = 2 * lane;             // out idx i0+2, i0+3 (2..129)
        const float* W = w2 + o0 * 96;
        float a[4][2];
#pragma unroll
        for (int oo = 0; oo < 4; ++oo) { const float bv = b2[o0 + oo]; a[oo][0] = bv; a[oo][1] = bv; }
#pragma unroll 4
        for (int c = 0; c < 32; ++c) {
            const float2 ha = *(const float2*)&hs[c][i0];
            const float2 hb = *(const float2*)&hs[c][i0 + 2];
#pragma unroll
            for (int oo = 0; oo < 4; ++oo) {
                const float wA = W[oo * 96 + c * 3 + 0];
                const float wB = W[oo * 96 + c * 3 + 1];
                const float wC = W[oo * 96 + c * 3 + 2];
                a[oo][0] = fmaf(wA, ha.x, fmaf(wB, ha.y, fmaf(wC, hb.x, a[oo][0])));
                a[oo][1] = fmaf(wA, ha.y, fmaf(wB, hb.x, fmaf(wC, hb.y, a[oo][1])));
            }
        }
        const int p0 = start + i0;           // pos of out idx i0+2
        if (p0 < NPOS) {
            const bool full = (p0 + 1 < NPOS);
#pragma unroll
            for (int oo = 0; oo < 4; ++oo) {
                const float2 xr = *(const float2*)&xs[o0 + oo][i0 + 2];
                const float r0 = fmaxf(xr.x + a[oo][0], 0.f);
                const float r1 = fmaxf(xr.y + a[oo][1], 0.f);
                float* ob = out + (size_t)(b * EMB + o0 + oo) * NPOS + p0;
                if (full) *(float2*)ob = make_float2(r0, r1);
                else ob[0] = r0;
            }
        }
    } else {
        // edge wave: out idx 130..134 for all 8 channel groups
        const int g2 = lane >> 3, p = lane & 7;
        if (p < 5) {
            const int o0e = g2 << 2;
            const int q = 130 + p;           // out idx; h taps stored at [q-2],[q-1],[q]
            float a[4];
#pragma unroll
            for (int oo = 0; oo < 4; ++oo) a[oo] = b2[o0e + oo];
#pragma unroll 4
            for (int c = 0; c < 32; ++c) {
                const float h0 = hs[c][q - 2], h1 = hs[c][q - 1], h2 = hs[c][q];
#pragma unroll
                for (int oo = 0; oo < 4; ++oo) {
                    const float wa = w2[(o0e + oo) * 96 + c * 3 + 0];
                    const float wb = w2[(o0e + oo) * 96 + c * 3 + 1];
                    const float wc = w2[(o0e + oo) * 96 + c * 3 + 2];
                    a[oo] = fmaf(wa, h0, fmaf(wb, h1, fmaf(wc, h2, a[oo])));
                }
            }
            const int pos = start + q - 2;   // start+128+p
            if (pos < NPOS) {
#pragma unroll
                for (int oo = 0; oo < 4; ++oo) {
                    const float r = fmaxf(xs[o0e + oo][q] + a[oo], 0.f);
                    out[(size_t)(b * EMB + o0e + oo) * NPOS + pos] = r;
                }
            }
        }
    }
}

extern "C" void kernel_launch(void* const* d_in, const int* in_sizes, int n_in,
                              void* d_out, int out_size, void* d_ws, size_t ws_size,
                              hipStream_t stream) {
    const float* inten = (const float*)d_in[0];
    const int* angle = (const int*)d_in[1];
    const float* emb = (const float*)d_in[2];
    const float* w1 = (const float*)d_in[3];
    const float* b1 = (const float*)d_in[4];
    const float* w2 = (const float*)d_in[5];
    const float* b2 = (const float*)d_in[6];
    float* out = (float*)d_out;

    float* part = (float*)d_ws;   // BB*396*64*4 = 405504 B

    moments_partial<<<BB * NBLK, 512, 0, stream>>>(inten, angle, emb, part);
    main_kernel<<<BB * NT, THR, 0, stream>>>(inten, part, w1, b1, w2, b2, out);
}

// Round 14
// 22.455 us; speedup vs baseline: 5.4080x; 1.0431x over previous
//
#include <hip/hip_runtime.h>

#define NPOS 8500
#define BB 4
#define EMB 32
#define KP 10              /* Taylor terms: truncation rel err <= e/10! ~ 7.5e-7 */
#define MOM (KP + KP * EMB) /* 330: S[10] + M[10][32] per batch */
#define NBLK 64            /* j-chunks per batch in k1 */
#define JPB 133            /* j's per chunk */
#define JPS 9              /* j's per 32-lane subgroup (16 subgroups) */
#define TOUT 133           /* output positions per tile; 64*133 = 8512 */
#define NT 64              /* tiles per batch -> grid = 256 exactly */
#define STG 137            /* staged x idx [0,137): pos start-2 .. start+134 */
#define STR 138            /* LDS row stride (floats), rows 8B-aligned */
#define THR 576            /* 9 waves: 8 conv waves + 1 edge wave */

__device__ __constant__ float c_invf[KP] = {
    1.f, 1.f, 0.5f, 1.f/6.f, 1.f/24.f, 1.f/120.f, 1.f/720.f, 1.f/5040.f,
    1.f/40320.f, 1.f/362880.f};

// shallow power tree: p[1..9] = v^k, depth <= 3 mults
__device__ __forceinline__ void powtree(float v, float* p) {
    const float v2 = v * v;
    const float v4 = v2 * v2;
    const float v8 = v4 * v4;
    p[1] = v;          p[2] = v2;         p[3] = v2 * v;
    p[4] = v4;         p[5] = v4 * v;     p[6] = v4 * v2;
    p[7] = v4 * p[3];  p[8] = v8;         p[9] = v8 * v;
}

// ---------------- kernel 1: partial moments (fixed order), grid = 256 exactly ----------------
// part layout: part[(b*MOM + i)*NBLK + blk]  (blk contiguous -> float4 reduce in main)
__global__ __launch_bounds__(512) void moments_partial(
    const float* __restrict__ inten, const int* __restrict__ angle,
    const float* __restrict__ emb, float* __restrict__ part)
{
    const int b = blockIdx.x >> 6;
    const int blk = blockIdx.x & 63;
    const int t = threadIdx.x;
    const int sub = t >> 5;                     // 16 subgroups of 32 lanes
    const int e = t & 31;                       // embed lane
    const int jlo = blk * JPB;
    const int jhi = min(jlo + JPB, NPOS);
    const int js = jlo + sub * JPS;
    const int je = min(js + JPS, jhi);

    float accM[KP], accS[KP];
#pragma unroll
    for (int k = 0; k < KP; ++k) { accM[k] = 0.f; accS[k] = 0.f; }

    const float* ib = inten + b * NPOS;
    const int* ab = angle + b * NPOS;
    int j = js;
    for (; j + 1 < je; j += 2) {                // two independent power chains
        const float va = ib[j] * 0.01f;
        const float vb = ib[j + 1] * 0.01f;
        const float eva = emb[ab[j] * EMB + e];
        const float evb = emb[ab[j + 1] * EMB + e];
        float pa[KP], pb[KP];
        powtree(va, pa);
        powtree(vb, pb);
        accM[0] += eva + evb;
        accS[0] += 2.0f;
#pragma unroll
        for (int k = 1; k < KP; ++k) {
            accM[k] = fmaf(pa[k], eva, accM[k]);
            accM[k] = fmaf(pb[k], evb, accM[k]);
            accS[k] += pa[k] + pb[k];
        }
    }
    if (j < je) {
        const float v = ib[j] * 0.01f;
        const float ev = emb[ab[j] * EMB + e];
        float p[KP];
        powtree(v, p);
        accM[0] += ev;
        accS[0] += 1.0f;
#pragma unroll
        for (int k = 1; k < KP; ++k) {
            accM[k] = fmaf(p[k], ev, accM[k]);
            accS[k] += p[k];
        }
    }

    // fold subgroup pairs within each wave (fixed order -> deterministic)
#pragma unroll
    for (int k = 0; k < KP; ++k) {
        accM[k] += __shfl_xor(accM[k], 32);
        accS[k] += __shfl_xor(accS[k], 32);
    }
    __shared__ float red[8][MOM];
    const int wv = t >> 6;
    if ((t & 32) == 0) {
#pragma unroll
        for (int k = 0; k < KP; ++k) red[wv][KP + k * EMB + e] = accM[k];
        if (e == 0) {
#pragma unroll
            for (int k = 0; k < KP; ++k) red[wv][k] = accS[k];
        }
    }
    __syncthreads();
    for (int i = t; i < MOM; i += 512) {
        float s = 0.f;
#pragma unroll
        for (int u = 0; u < 8; ++u) s += red[u][i];
        part[((size_t)b * MOM + i) * NBLK + blk] = s;
    }
}

// ---------------- kernel 2: reduce + x(Horner) -> conv1+relu -> conv2+res+relu ----------------
// Weights/biases via wave-uniform scalar loads from ORIGINAL layout (no transpose, no LDS).
__global__ __launch_bounds__(THR) void main_kernel(
    const float* __restrict__ inten, const float* __restrict__ part,
    const float* __restrict__ w1, const float* __restrict__ b1,
    const float* __restrict__ w2, const float* __restrict__ b2,
    float* __restrict__ out)
{
    __shared__ float moms[MOM];
    __shared__ float redq[4][MOM];  // quarter partials of the part-reduce
    __shared__ float xs[EMB][STR];  // x idx 0..136 (pos = start-2+idx)
    __shared__ float hs[EMB][STR];  // h idx j stored at [j-1], j in 1..135

    const int t = threadIdx.x;
    const int b = blockIdx.x >> 6;      // NT = 64
    const int tile = blockIdx.x & 63;
    const int start = tile * TOUT;
    const int e = t & 31;

    // ---- preload this thread's x-gen inputs (u<0 == invalid sentinel) ----
    float uu[8];
#pragma unroll
    for (int q = 0; q < 8; ++q) {
        const int i = t + q * THR;
        float u = -1.0f;
        if (i < STG * EMB) {
            const int pos = i >> 5;
            const int gp = start - 2 + pos;
            if (gp >= 0 && gp < NPOS) u = inten[b * NPOS + gp] * 0.01f;
        }
        uu[q] = u;
    }

    // ---- reduce this batch's partials: 1320 independent (coeff, quarter) items ----
    // item m: coeff i = m>>2, quarter q = m&3 -> sums part[...][q*16 .. q*16+15]
#pragma unroll
    for (int mq = 0; mq < 3; ++mq) {
        const int m = t + mq * THR;
        if (m < 4 * MOM) {
            const int i = m >> 2, q = m & 3;
            const float4* pr = (const float4*)&part[((size_t)b * MOM + i) * NBLK + q * 16];
            const float4 s0 = pr[0], s1 = pr[1], s2 = pr[2], s3 = pr[3];
            float4 sa;
            sa.x = (s0.x + s1.x) + (s2.x + s3.x);
            sa.y = (s0.y + s1.y) + (s2.y + s3.y);
            sa.z = (s0.z + s1.z) + (s2.z + s3.z);
            sa.w = (s0.w + s1.w) + (s2.w + s3.w);
            redq[q][i] = (sa.x + sa.y) + (sa.z + sa.w);
        }
    }
    __syncthreads();
    if (t < MOM) {
        const float s = (redq[0][t] + redq[1][t]) + (redq[2][t] + redq[3][t]);
        const int k = (t < KP) ? t : ((t - KP) >> 5);
        moms[t] = s * c_invf[k];
    }
    __syncthreads();

    // per-thread Horner coefficients (pre-scaled by 1/k!)
    float Mreg[KP], Sreg[KP];
#pragma unroll
    for (int k = 0; k < KP; ++k) {
        Mreg[k] = moms[KP + k * EMB + e];
        Sreg[k] = moms[k];
    }

    // ---- x-gen from preloaded u ----
#pragma unroll
    for (int q = 0; q < 8; ++q) {
        const int i = t + q * THR;
        if (i < STG * EMB) {
            const int pos = i >> 5;
            const float u = uu[q];
            const bool valid = (u >= 0.f);
            const float uc = valid ? u : 0.f;
            float num = Mreg[KP - 1], den = Sreg[KP - 1];
#pragma unroll
            for (int k = KP - 2; k >= 0; --k) {
                num = fmaf(num, uc, Mreg[k]);
                den = fmaf(den, uc, Sreg[k]);
            }
            const float rd = valid ? __builtin_amdgcn_rcpf(den) : 0.f;
            xs[e][pos] = num * rd;
        }
    }
    __syncthreads();

    const int wv = t >> 6;       // wave id 0..8
    const int lane = t & 63;

    // ---- conv1 + relu -> hs ----
    if (wv < 8) {
        const int o0 = __builtin_amdgcn_readfirstlane(wv << 2);
        const int i0 = 2 * lane;             // h idx i0+1, i0+2 (1..128)
        const float* W = w1 + o0 * 96;       // rows o0..o0+3, [o][c*3+d]
        float a[4][2];
#pragma unroll
        for (int oo = 0; oo < 4; ++oo) { const float bv = b1[o0 + oo]; a[oo][0] = bv; a[oo][1] = bv; }
#pragma unroll 4
        for (int c = 0; c < 32; ++c) {
            const float2 xa = *(const float2*)&xs[c][i0];
            const float2 xb = *(const float2*)&xs[c][i0 + 2];
#pragma unroll
            for (int oo = 0; oo < 4; ++oo) {
                const float wA = W[oo * 96 + c * 3 + 0];   // SGPR-uniform
                const float wB = W[oo * 96 + c * 3 + 1];
                const float wC = W[oo * 96 + c * 3 + 2];
                a[oo][0] = fmaf(wA, xa.x, fmaf(wB, xa.y, fmaf(wC, xb.x, a[oo][0])));
                a[oo][1] = fmaf(wA, xa.y, fmaf(wB, xb.x, fmaf(wC, xb.y, a[oo][1])));
            }
        }
        const int gp0 = start - 1 + i0;      // pos of h idx i0+1
        const bool v0 = (gp0 >= 0) && (gp0 < NPOS);
        const bool v1 = (gp0 + 1 >= 0) && (gp0 + 1 < NPOS);
#pragma unroll
        for (int oo = 0; oo < 4; ++oo) {
            float2 hv;
            hv.x = v0 ? fmaxf(a[oo][0], 0.f) : 0.f;
            hv.y = v1 ? fmaxf(a[oo][1], 0.f) : 0.f;
            *(float2*)&hs[o0 + oo][i0] = hv;
        }
    } else {
        // edge wave: h idx 129..135 for all 8 channel groups
        const int g2 = lane >> 3, p = lane & 7;
        if (p < 7) {
            const int o0e = g2 << 2;
            const int j = 129 + p;           // h idx
            float a[4];
#pragma unroll
            for (int oo = 0; oo < 4; ++oo) a[oo] = b1[o0e + oo];
#pragma unroll 4
            for (int c = 0; c < 32; ++c) {
                const float x0 = xs[c][j - 1], x1 = xs[c][j], x2 = xs[c][j + 1];
#pragma unroll
                for (int oo = 0; oo < 4; ++oo) {
                    const float wa = w1[(o0e + oo) * 96 + c * 3 + 0];
                    const float wb = w1[(o0e + oo) * 96 + c * 3 + 1];
                    const float wc = w1[(o0e + oo) * 96 + c * 3 + 2];
                    a[oo] = fmaf(wa, x0, fmaf(wb, x1, fmaf(wc, x2, a[oo])));
                }
            }
            const int gp = start - 2 + j;    // >= 127, only upper clamp needed
            const bool v = gp < NPOS;
#pragma unroll
            for (int oo = 0; oo < 4; ++oo)
                hs[o0e + oo][j - 1] = v ? fmaxf(a[oo], 0.f) : 0.f;
        }
    }
    __syncthreads();

    // ---- conv2 + residual + relu -> out ----
    if (wv < 8) {
        const int o0 = __builtin_amdgcn_readfirstlane(wv << 2);
        const int i0 = 2 * lane;             // out idx i0+2, i0+3 (2..129)
        const float* W = w2 + o0 * 96;
        float a[4][2];
#pragma unroll
        for (int oo = 0; oo < 4; ++oo) { const float bv = b2[o0 + oo]; a[oo][0] = bv; a[oo][1] = bv; }
#pragma unroll 4
        for (int c = 0; c < 32; ++c) {
            const float2 ha = *(const float2*)&hs[c][i0];
            const float2 hb = *(const float2*)&hs[c][i0 + 2];
#pragma unroll
            for (int oo = 0; oo < 4; ++oo) {
                const float wA = W[oo * 96 + c * 3 + 0];
                const float wB = W[oo * 96 + c * 3 + 1];
                const float wC = W[oo * 96 + c * 3 + 2];
                a[oo][0] = fmaf(wA, ha.x, fmaf(wB, ha.y, fmaf(wC, hb.x, a[oo][0])));
                a[oo][1] = fmaf(wA, ha.y, fmaf(wB, hb.x, fmaf(wC, hb.y, a[oo][1])));
            }
        }
        const int p0 = start + i0;           // pos of out idx i0+2
        if (p0 < NPOS) {
            const bool full = (p0 + 1 < NPOS);
#pragma unroll
            for (int oo = 0; oo < 4; ++oo) {
                const float2 xr = *(const float2*)&xs[o0 + oo][i0 + 2];
                const float r0 = fmaxf(xr.x + a[oo][0], 0.f);
                const float r1 = fmaxf(xr.y + a[oo][1], 0.f);
                float* ob = out + (size_t)(b * EMB + o0 + oo) * NPOS + p0;
                if (full) *(float2*)ob = make_float2(r0, r1);
                else ob[0] = r0;
            }
        }
    } else {
        // edge wave: out idx 130..134 for all 8 channel groups
        const int g2 = lane >> 3, p = lane & 7;
        if (p < 5) {
            const int o0e = g2 << 2;
            const int q = 130 + p;           // out idx; h taps stored at [q-2],[q-1],[q]
            float a[4];
#pragma unroll
            for (int oo = 0; oo < 4; ++oo) a[oo] = b2[o0e + oo];
#pragma unroll 4
            for (int c = 0; c < 32; ++c) {
                const float h0 = hs[c][q - 2], h1 = hs[c][q - 1], h2 = hs[c][q];
#pragma unroll
                for (int oo = 0; oo < 4; ++oo) {
                    const float wa = w2[(o0e + oo) * 96 + c * 3 + 0];
                    const float wb = w2[(o0e + oo) * 96 + c * 3 + 1];
                    const float wc = w2[(o0e + oo) * 96 + c * 3 + 2];
                    a[oo] = fmaf(wa, h0, fmaf(wb, h1, fmaf(wc, h2, a[oo])));
                }
            }
            const int pos = start + q - 2;   // start+128+p
            if (pos < NPOS) {
#pragma unroll
                for (int oo = 0; oo < 4; ++oo) {
                    const float r = fmaxf(xs[o0e + oo][q] + a[oo], 0.f);
                    out[(size_t)(b * EMB + o0e + oo) * NPOS + pos] = r;
                }
            }
        }
    }
}

extern "C" void kernel_launch(void* const* d_in, const int* in_sizes, int n_in,
                              void* d_out, int out_size, void* d_ws, size_t ws_size,
                              hipStream_t stream) {
    const float* inten = (const float*)d_in[0];
    const int* angle = (const int*)d_in[1];
    const float* emb = (const float*)d_in[2];
    const float* w1 = (const float*)d_in[3];
    const float* b1 = (const float*)d_in[4];
    const float* w2 = (const float*)d_in[5];
    const float* b2 = (const float*)d_in[6];
    float* out = (float*)d_out;

    float* part = (float*)d_ws;   // BB*330*64*4 = 337920 B

    moments_partial<<<BB * NBLK, 512, 0, stream>>>(inten, angle, emb, part);
    main_kernel<<<BB * NT, THR, 0, stream>>>(inten, part, w1, b1, w2, b2, out);
}